// Round 10
// baseline (388.399 us; speedup 1.0000x reference)
//
#include <hip/hip_runtime.h>
#include <stdint.h>

#define DIM 2048
#define SEQ 2048
#define NHEADS 16
#define HDIM 128
#define BSZ 2
#define ROWS (BSZ*SEQ)   // 4096

typedef uint16_t u16;
typedef __attribute__((ext_vector_type(8))) short bf16x8;
typedef __attribute__((ext_vector_type(4))) short bf16x4;
typedef __attribute__((ext_vector_type(4))) float fx4;
typedef __attribute__((ext_vector_type(4))) uint16_t u16x4;

typedef const __attribute__((address_space(1))) uint32_t* gp_t;
typedef __attribute__((address_space(3))) uint32_t* lp_t;
#define GLL16(g, l) __builtin_amdgcn_global_load_lds((gp_t)(g), (lp_t)(l), 16, 0, 0)

__device__ inline u16 f2bf(float f) {
  union { float f; uint32_t u; } v; v.f = f;
  uint32_t u = v.u;
  u += 0x7FFFu + ((u >> 16) & 1u);   // RNE
  return (u16)(u >> 16);
}
__device__ inline float bf2f(u16 h) {
  union { uint32_t u; float f; } v; v.u = ((uint32_t)h) << 16;
  return v.f;
}

// ---------------------------------------------------------------- fused convert fp32 -> bf16
__global__ __launch_bounds__(256) void cvt5_kernel(const float* __restrict__ sx,
    const float* __restrict__ s1, const float* __restrict__ s2,
    const float* __restrict__ s3, const float* __restrict__ s4,
    u16* __restrict__ dst) {
  const int XC = (ROWS * DIM) / 4;
  const int WC = (DIM * DIM) / 4;          // 2^20
  int i = blockIdx.x * 256 + threadIdx.x;
  const float* src;
  int off;
  if (i < XC) { src = sx; off = i; }
  else {
    int t = i - XC;
    int w = t >> 20;
    off = t & (WC - 1);
    src = (w == 0) ? s1 : (w == 1) ? s2 : (w == 2) ? s3 : s4;
  }
  fx4 f = *(const fx4*)(src + (size_t)off * 4);
  u16x4 o;
  o[0] = f2bf(f[0]); o[1] = f2bf(f[1]); o[2] = f2bf(f[2]); o[3] = f2bf(f[3]);
  *(u16x4*)(dst + (size_t)i * 4) = o;
}

// ---------------------------------------------------------------- QKV GEMM: 256x128 tile, 4-phase schedule
// 768 blocks = 3.0 exact rounds; r2 measured-best skeleton (sched_barrier-pinned counted
// waits, 2-half-tile prefetch, vmcnt(4) boundary), T2 swizzle, T5 setprio, T1 XCD swizzle.
// Epilogue: RoPE fused for z<2; V (z==2) written TRANSPOSED into vtg via LDS.
#define BM 256
#define BN 128
#define BK 64
#define NT (DIM / BK)         // 32
#define BUFSZ ((BM + BN) * BK) // 24576 u16 per K-tile buffer

__global__ __launch_bounds__(512, 2) void gemm_qkv8(const u16* __restrict__ A,
    const u16* __restrict__ B0, const u16* __restrict__ B1, const u16* __restrict__ B2,
    u16* __restrict__ C0, u16* __restrict__ C1, u16* __restrict__ vtg,
    const float* __restrict__ fcos, const float* __restrict__ fsin) {
  __shared__ __align__(16) u16 sm[2 * BUFSZ];   // 96 KiB

  const int tid  = threadIdx.x;
  const int lane = tid & 63, wave = tid >> 6;
  const int l16  = lane & 15, quad = lane >> 4;
  const int wm   = wave >> 2;        // 0..1 (M half: 128 rows)
  const int wn   = wave & 3;         // 0..3 (N quarter: 32 cols)

  // XCD-aware bijective swizzle over 768 blocks (96 per XCD)
  int t = (blockIdx.x & 7) * 96 + (blockIdx.x >> 3);
  const int z   = t >> 8;            // 0..2 : Q,K,V
  const int rem = t & 255;
  const int M0  = (rem >> 4) * BM;
  const int N0  = (rem & 15) * BN;
  const u16* B = (z == 0) ? B0 : (z == 1) ? B1 : B2;

  // stage-side: half-tile = 128 rows x 64 cols (16 KiB) = 2 loads/thread.
  // LDS dest LINEAR; global source chunk inverse-swizzled.
  const int u0 = tid, u1 = 512 + tid;
  const int rl0 = u0 >> 3, ch0 = (u0 & 7) ^ (rl0 & 7);
  const int rl1 = u1 >> 3, ch1 = (u1 & 7) ^ (rl1 & 7);

  // read-side: frag (row, kh) at elem row*64 + ((kh*4+quad)^(row&7))*8 ; row&7 == l16&7
  const int sw  = l16 & 7;
  const int ka0 = (quad ^ sw) * 8;          // kh=0 swizzled chunk offset (elems)
  const int ka1 = ((4 + quad) ^ sw) * 8;    // kh=1
  const int rowA = (wm * 128 + l16) * BK;   // A rows 0..255 contiguous (halves adjacent)
  const int rowB = (wn * 32  + l16) * BK;   // B rows 0..127

// stage A half-tile h (rows h*128..h*128+127) of K-tile kt2 into buf[kt2&1]
#define STGA(h, kt2) do { if ((kt2) < NT) {                                              \
    const u16* _g = A + (size_t)(M0 + (h) * 128) * DIM + (kt2) * BK;                     \
    u16* _l = sm + ((kt2) & 1) * BUFSZ + (h) * 8192 + wave * 512;                        \
    GLL16(_g + (size_t)rl0 * DIM + ch0 * 8, _l);                                         \
    GLL16(_g + (size_t)rl1 * DIM + ch1 * 8, _l + 4096); } } while (0)
// stage the single B half-tile (rows 0..127) of K-tile kt2
#define STGB(kt2) do { if ((kt2) < NT) {                                                 \
    const u16* _g = B + (size_t)N0 * DIM + (kt2) * BK;                                   \
    u16* _l = sm + ((kt2) & 1) * BUFSZ + 16384 + wave * 512;                             \
    GLL16(_g + (size_t)rl0 * DIM + ch0 * 8, _l);                                         \
    GLL16(_g + (size_t)rl1 * DIM + ch1 * 8, _l + 4096); } } while (0)

  // prologue: tile0 {B,A0,A1} + tile1 {B,A0} = 10 loads; keep last 2 half-tiles in flight
  STGB(0); STGA(0, 0); STGA(1, 0);
  STGB(1); STGA(0, 1);
  asm volatile("s_waitcnt vmcnt(4)" ::: "memory");
  __builtin_amdgcn_s_barrier();

  fx4 acc[8][2];
#pragma unroll
  for (int m = 0; m < 8; ++m)
#pragma unroll
    for (int n = 0; n < 2; ++n) acc[m][n] = fx4{0.f, 0.f, 0.f, 0.f};

  bf16x8 af[4][2], b0[2], b1[2];

  for (int kt = 0; kt < NT; ++kt) {
    const u16* Ab = sm + (kt & 1) * BUFSZ;
    const u16* Bb = Ab + 16384;

    // ---- ph0: read A-low(8) + B-n0(2); stage (kt+1).A1; MFMA m-low x n0
#pragma unroll
    for (int m = 0; m < 4; ++m) {
      af[m][0] = *(const bf16x8*)(Ab + rowA + m * (16 * BK) + ka0);
      af[m][1] = *(const bf16x8*)(Ab + rowA + m * (16 * BK) + ka1);
    }
    b0[0] = *(const bf16x8*)(Bb + rowB + ka0);
    b0[1] = *(const bf16x8*)(Bb + rowB + ka1);
    STGA(1, kt + 1);
    asm volatile("s_waitcnt lgkmcnt(8)" ::: "memory");
    __builtin_amdgcn_sched_barrier(0);
    __builtin_amdgcn_s_barrier();
    asm volatile("s_waitcnt lgkmcnt(0)" ::: "memory");
    __builtin_amdgcn_sched_barrier(0);
    __builtin_amdgcn_s_setprio(1);
#pragma unroll
    for (int m = 0; m < 4; ++m) {
      acc[m][0] = __builtin_amdgcn_mfma_f32_16x16x32_bf16(af[m][0], b0[0], acc[m][0], 0, 0, 0);
      acc[m][0] = __builtin_amdgcn_mfma_f32_16x16x32_bf16(af[m][1], b0[1], acc[m][0], 0, 0, 0);
    }
    __builtin_amdgcn_s_setprio(0);
    __builtin_amdgcn_s_barrier();

    // ---- ph1: read B-n1(2); MFMA m-low x n1
    b1[0] = *(const bf16x8*)(Bb + rowB + 16 * BK + ka0);
    b1[1] = *(const bf16x8*)(Bb + rowB + 16 * BK + ka1);
    __builtin_amdgcn_s_barrier();
    asm volatile("s_waitcnt lgkmcnt(0)" ::: "memory");
    __builtin_amdgcn_sched_barrier(0);
    __builtin_amdgcn_s_setprio(1);
#pragma unroll
    for (int m = 0; m < 4; ++m) {
      acc[m][1] = __builtin_amdgcn_mfma_f32_16x16x32_bf16(af[m][0], b1[0], acc[m][1], 0, 0, 0);
      acc[m][1] = __builtin_amdgcn_mfma_f32_16x16x32_bf16(af[m][1], b1[1], acc[m][1], 0, 0, 0);
    }
    __builtin_amdgcn_s_setprio(0);
    __builtin_amdgcn_s_barrier();

    // ---- ph2: read A-high(8); stage (kt+2).B (B reads of this tile finished in ph1);
    //          MFMA m-high x n1
#pragma unroll
    for (int m = 0; m < 4; ++m) {
      af[m][0] = *(const bf16x8*)(Ab + rowA + (m + 4) * (16 * BK) + ka0);
      af[m][1] = *(const bf16x8*)(Ab + rowA + (m + 4) * (16 * BK) + ka1);
    }
    STGB(kt + 2);
    __builtin_amdgcn_s_barrier();
    asm volatile("s_waitcnt lgkmcnt(0)" ::: "memory");
    __builtin_amdgcn_sched_barrier(0);
    __builtin_amdgcn_s_setprio(1);
#pragma unroll
    for (int m = 0; m < 4; ++m) {
      acc[m + 4][1] = __builtin_amdgcn_mfma_f32_16x16x32_bf16(af[m][0], b1[0], acc[m + 4][1], 0, 0, 0);
      acc[m + 4][1] = __builtin_amdgcn_mfma_f32_16x16x32_bf16(af[m][1], b1[1], acc[m + 4][1], 0, 0, 0);
    }
    __builtin_amdgcn_s_setprio(0);
    __builtin_amdgcn_s_barrier();

    // ---- ph3: no ds-reads (b0 in regs); stage (kt+2).A0 (A reads finished in ph2);
    //          MFMA m-high x n0; boundary vmcnt + barrier
    STGA(0, kt + 2);
    __builtin_amdgcn_s_barrier();
    __builtin_amdgcn_s_setprio(1);
#pragma unroll
    for (int m = 0; m < 4; ++m) {
      acc[m + 4][0] = __builtin_amdgcn_mfma_f32_16x16x32_bf16(af[m][0], b0[0], acc[m + 4][0], 0, 0, 0);
      acc[m + 4][0] = __builtin_amdgcn_mfma_f32_16x16x32_bf16(af[m][1], b0[1], acc[m + 4][0], 0, 0, 0);
    }
    __builtin_amdgcn_s_setprio(0);
    // tile kt+1 fully staged when <= 2 half-tiles (= (kt+2).B/A0) outstanding
    if (kt < NT - 2) asm volatile("s_waitcnt vmcnt(4)" ::: "memory");
    else             asm volatile("s_waitcnt vmcnt(0)" ::: "memory");
    __builtin_amdgcn_sched_barrier(0);
    __builtin_amdgcn_s_barrier();
  }
#undef STGA
#undef STGB

  if (z < 2) {
    // epilogue Q/K: C[row=quad*4+r][col=l16] per 16x16 tile with fused RoPE.
    // Adjacent head-features (2p,2p+1) sit in adjacent lanes -> shfl_xor(.,1).
    u16* C = (z == 0) ? C0 : C1;
    u16* Cr = C + (size_t)(M0 + wm * 128 + quad * 4) * DIM + N0 + wn * 32 + l16;
#pragma unroll
    for (int mt = 0; mt < 8; ++mt)
#pragma unroll
      for (int r = 0; r < 4; ++r) {
        int s = (M0 + wm * 128 + mt * 16 + quad * 4 + r) & (SEQ - 1);
        const float* cb = fcos + s * 64;
        const float* sb = fsin + s * 64;
#pragma unroll
        for (int nt = 0; nt < 2; ++nt) {
          int p = (wn * 32 + nt * 16 + l16) >> 1;   // N0 multiple of 128 -> head-local
          float val = acc[mt][nt][r];
          float par = __shfl_xor(val, 1);
          float c = cb[p], sn = sb[p];
          float out = (l16 & 1) ? (par * sn + val * c) : (val * c - par * sn);
          Cr[(size_t)(mt * 16 + r) * DIM + nt * 16] = f2bf(out);
        }
      }
  } else {
    // epilogue V: transpose through LDS (staging buffers dead), write vtg[bh][d][s].
    // Tile = 256 s-rows x 128 d-cols = exactly one head. T[128 cols][256 rows] = 64 KB.
    u16 (*T)[256] = reinterpret_cast<u16 (*)[256]>(sm);
    __syncthreads();   // all waves past their last staging-buffer access
#pragma unroll
    for (int mt = 0; mt < 8; ++mt)
#pragma unroll
      for (int nt = 0; nt < 2; ++nt) {
        int col = wn * 32 + nt * 16 + l16;          // d within head: 0..127
        int rowb = (wm * 128 + mt * 16 + quad * 4) ^ ((col & 7) << 3);
        u16x4 p;
        p[0] = f2bf(acc[mt][nt][0]); p[1] = f2bf(acc[mt][nt][1]);
        p[2] = f2bf(acc[mt][nt][2]); p[3] = f2bf(acc[mt][nt][3]);
        *(u16x4*)&T[col][rowb] = p;
      }
    __syncthreads();
    const int b  = M0 >> 11;             // batch
    const int s0 = M0 & (SEQ - 1);
    const int h  = N0 >> 7;              // single head this tile covers
#pragma unroll
    for (int i = 0; i < 8; ++i) {
      int c = i * 512 + tid;             // 4096 16B chunks
      int col = c >> 5;                  // d: 0..127
      int s8 = (c & 31) * 8;             // s offset 0..248
      bf16x8 v8 = *(const bf16x8*)&T[col][s8 ^ ((col & 7) << 3)];
      *(bf16x8*)(vtg + ((size_t)(b * NHEADS + h) * HDIM + col) * SEQ + s0 + s8) = v8;
    }
  }
}

// ---------------------------------------------------------------- output GEMM: same 256x128
// 4-phase structure (duplicated verbatim from gemm_qkv8 to avoid perturbing its codegen).
// Grid 16 M x 16 N = 256 blocks = exactly 1.0 rounds. f32 epilogue.
__global__ __launch_bounds__(512, 2) void gemm_out8(const u16* __restrict__ A,
                                                    const u16* __restrict__ B,
                                                    float* __restrict__ C) {
  __shared__ __align__(16) u16 sm[2 * BUFSZ];   // 96 KiB

  const int tid  = threadIdx.x;
  const int lane = tid & 63, wave = tid >> 6;
  const int l16  = lane & 15, quad = lane >> 4;
  const int wm   = wave >> 2;
  const int wn   = wave & 3;

  // XCD-aware bijective swizzle over 256 blocks (32 per XCD)
  int t = (blockIdx.x & 7) * 32 + (blockIdx.x >> 3);
  const int M0  = (t >> 4) * BM;
  const int N0  = (t & 15) * BN;

  const int u0 = tid, u1 = 512 + tid;
  const int rl0 = u0 >> 3, ch0 = (u0 & 7) ^ (rl0 & 7);
  const int rl1 = u1 >> 3, ch1 = (u1 & 7) ^ (rl1 & 7);

  const int sw  = l16 & 7;
  const int ka0 = (quad ^ sw) * 8;
  const int ka1 = ((4 + quad) ^ sw) * 8;
  const int rowA = (wm * 128 + l16) * BK;
  const int rowB = (wn * 32  + l16) * BK;

#define STGA(h, kt2) do { if ((kt2) < NT) {                                              \
    const u16* _g = A + (size_t)(M0 + (h) * 128) * DIM + (kt2) * BK;                     \
    u16* _l = sm + ((kt2) & 1) * BUFSZ + (h) * 8192 + wave * 512;                        \
    GLL16(_g + (size_t)rl0 * DIM + ch0 * 8, _l);                                         \
    GLL16(_g + (size_t)rl1 * DIM + ch1 * 8, _l + 4096); } } while (0)
#define STGB(kt2) do { if ((kt2) < NT) {                                                 \
    const u16* _g = B + (size_t)N0 * DIM + (kt2) * BK;                                   \
    u16* _l = sm + ((kt2) & 1) * BUFSZ + 16384 + wave * 512;                             \
    GLL16(_g + (size_t)rl0 * DIM + ch0 * 8, _l);                                         \
    GLL16(_g + (size_t)rl1 * DIM + ch1 * 8, _l + 4096); } } while (0)

  STGB(0); STGA(0, 0); STGA(1, 0);
  STGB(1); STGA(0, 1);
  asm volatile("s_waitcnt vmcnt(4)" ::: "memory");
  __builtin_amdgcn_s_barrier();

  fx4 acc[8][2];
#pragma unroll
  for (int m = 0; m < 8; ++m)
#pragma unroll
    for (int n = 0; n < 2; ++n) acc[m][n] = fx4{0.f, 0.f, 0.f, 0.f};

  bf16x8 af[4][2], b0[2], b1[2];

  for (int kt = 0; kt < NT; ++kt) {
    const u16* Ab = sm + (kt & 1) * BUFSZ;
    const u16* Bb = Ab + 16384;

    // ---- ph0
#pragma unroll
    for (int m = 0; m < 4; ++m) {
      af[m][0] = *(const bf16x8*)(Ab + rowA + m * (16 * BK) + ka0);
      af[m][1] = *(const bf16x8*)(Ab + rowA + m * (16 * BK) + ka1);
    }
    b0[0] = *(const bf16x8*)(Bb + rowB + ka0);
    b0[1] = *(const bf16x8*)(Bb + rowB + ka1);
    STGA(1, kt + 1);
    asm volatile("s_waitcnt lgkmcnt(8)" ::: "memory");
    __builtin_amdgcn_sched_barrier(0);
    __builtin_amdgcn_s_barrier();
    asm volatile("s_waitcnt lgkmcnt(0)" ::: "memory");
    __builtin_amdgcn_sched_barrier(0);
    __builtin_amdgcn_s_setprio(1);
#pragma unroll
    for (int m = 0; m < 4; ++m) {
      acc[m][0] = __builtin_amdgcn_mfma_f32_16x16x32_bf16(af[m][0], b0[0], acc[m][0], 0, 0, 0);
      acc[m][0] = __builtin_amdgcn_mfma_f32_16x16x32_bf16(af[m][1], b0[1], acc[m][0], 0, 0, 0);
    }
    __builtin_amdgcn_s_setprio(0);
    __builtin_amdgcn_s_barrier();

    // ---- ph1
    b1[0] = *(const bf16x8*)(Bb + rowB + 16 * BK + ka0);
    b1[1] = *(const bf16x8*)(Bb + rowB + 16 * BK + ka1);
    __builtin_amdgcn_s_barrier();
    asm volatile("s_waitcnt lgkmcnt(0)" ::: "memory");
    __builtin_amdgcn_sched_barrier(0);
    __builtin_amdgcn_s_setprio(1);
#pragma unroll
    for (int m = 0; m < 4; ++m) {
      acc[m][1] = __builtin_amdgcn_mfma_f32_16x16x32_bf16(af[m][0], b1[0], acc[m][1], 0, 0, 0);
      acc[m][1] = __builtin_amdgcn_mfma_f32_16x16x32_bf16(af[m][1], b1[1], acc[m][1], 0, 0, 0);
    }
    __builtin_amdgcn_s_setprio(0);
    __builtin_amdgcn_s_barrier();

    // ---- ph2
#pragma unroll
    for (int m = 0; m < 4; ++m) {
      af[m][0] = *(const bf16x8*)(Ab + rowA + (m + 4) * (16 * BK) + ka0);
      af[m][1] = *(const bf16x8*)(Ab + rowA + (m + 4) * (16 * BK) + ka1);
    }
    STGB(kt + 2);
    __builtin_amdgcn_s_barrier();
    asm volatile("s_waitcnt lgkmcnt(0)" ::: "memory");
    __builtin_amdgcn_sched_barrier(0);
    __builtin_amdgcn_s_setprio(1);
#pragma unroll
    for (int m = 0; m < 4; ++m) {
      acc[m + 4][1] = __builtin_amdgcn_mfma_f32_16x16x32_bf16(af[m][0], b1[0], acc[m + 4][1], 0, 0, 0);
      acc[m + 4][1] = __builtin_amdgcn_mfma_f32_16x16x32_bf16(af[m][1], b1[1], acc[m + 4][1], 0, 0, 0);
    }
    __builtin_amdgcn_s_setprio(0);
    __builtin_amdgcn_s_barrier();

    // ---- ph3
    STGA(0, kt + 2);
    __builtin_amdgcn_s_barrier();
    __builtin_amdgcn_s_setprio(1);
#pragma unroll
    for (int m = 0; m < 4; ++m) {
      acc[m + 4][0] = __builtin_amdgcn_mfma_f32_16x16x32_bf16(af[m][0], b0[0], acc[m + 4][0], 0, 0, 0);
      acc[m + 4][0] = __builtin_amdgcn_mfma_f32_16x16x32_bf16(af[m][1], b0[1], acc[m + 4][0], 0, 0, 0);
    }
    __builtin_amdgcn_s_setprio(0);
    if (kt < NT - 2) asm volatile("s_waitcnt vmcnt(4)" ::: "memory");
    else             asm volatile("s_waitcnt vmcnt(0)" ::: "memory");
    __builtin_amdgcn_sched_barrier(0);
    __builtin_amdgcn_s_barrier();
  }
#undef STGA
#undef STGB

  // epilogue: f32 C[row=quad*4+r][col=l16] per 16x16 tile
  float* Cr = C + (size_t)(M0 + wm * 128 + quad * 4) * DIM + N0 + wn * 32 + l16;
#pragma unroll
  for (int mt = 0; mt < 8; ++mt)
#pragma unroll
    for (int nt = 0; nt < 2; ++nt)
#pragma unroll
      for (int r = 0; r < 4; ++r)
        Cr[(size_t)(mt * 16 + r) * DIM + nt * 16] = acc[mt][nt][r];
}

// ---------------------------------------------------------------- flash attention, S^T form
// S^T = K·Q^T so P^T (C-layout: col=q=lane&15, row=kv=quad*4+reg) is directly the
// B-operand of mfma_f32_16x16x16bf16_1k (n=lane&15, k=quad*4+j): PV needs NO LDS
// round-trip. O accumulates as O^T[d][q]; one LDS transpose at the end.
// Br=128 (4 waves x 2 q-tiles of 16), Bc=64.
struct SMemS { u16 Ks[64][136]; u16 Vt[128][72]; };
union SMemU { SMemS s; u16 Ot[4][32][136]; };

__global__ __launch_bounds__(256, 2) void attn_kernel(const u16* __restrict__ qm,
                                                      const u16* __restrict__ km,
                                                      const u16* __restrict__ vtg,
                                                      u16* __restrict__ ao) {
  __shared__ __align__(16) SMemU sm;
  const int tid = threadIdx.x;
  const int lane = tid & 63, wave = tid >> 6;
  const int l16 = lane & 15, quad = lane >> 4;
  const int idx = blockIdx.x;
  const int bh = idx & 31;
  const int j = idx >> 5;
  const int qt = (j < 8) ? (15 - j) : (j - 8);   // complementary pairing
  const int b = bh >> 4, h = bh & 15;
  const int q0 = qt * 128;
  const size_t brow = (size_t)b * SEQ;
  const int hc = h * HDIM;
  const size_t vbase = (size_t)bh * HDIM * SEQ;
  const int nkt = 2 * qt + 2;

  // Q as B-operand frags: B[n=q=l16][k=d=quad*8+j]
  bf16x8 aq[2][4];
#pragma unroll
  for (int nt = 0; nt < 2; ++nt) {
    size_t qbase = (brow + q0 + wave * 32 + nt * 16 + l16) * DIM + hc;
#pragma unroll
    for (int dc = 0; dc < 4; ++dc)
      aq[nt][dc] = *(const bf16x8*)(qm + qbase + dc * 32 + quad * 8);
  }
  fx4 o[2][8];   // O^T tiles: [q-tile][d-tile], C-layout col=q=l16, row=d=quad*4+r
#pragma unroll
  for (int nt = 0; nt < 2; ++nt)
#pragma unroll
    for (int dt = 0; dt < 8; ++dt) o[nt][dt] = fx4{0.f, 0.f, 0.f, 0.f};
  float mr[2] = {-3e38f, -3e38f}, lr[2] = {0.f, 0.f};   // per-lane: q = l16 of each tile

  bf16x8 kreg[4], vreg[4];
#pragma unroll
  for (int i = 0; i < 4; ++i) {
    int c = i * 256 + tid;
    kreg[i] = *(const bf16x8*)(km + (brow + (c >> 4)) * DIM + hc + (c & 15) * 8);
    vreg[i] = *(const bf16x8*)(vtg + vbase + (size_t)(c >> 3) * SEQ + (c & 7) * 8);
  }

  for (int kt = 0; kt < nkt; ++kt) {
    __syncthreads();
#pragma unroll
    for (int i = 0; i < 4; ++i) {
      int c = i * 256 + tid;
      *(bf16x8*)&sm.s.Ks[c >> 4][(c & 15) * 8] = kreg[i];
      *(bf16x8*)&sm.s.Vt[c >> 3][(c & 7) * 8] = vreg[i];
    }
    __syncthreads();
    if (kt + 1 < nkt) {
      const int kv1 = (kt + 1) * 64;
#pragma unroll
      for (int i = 0; i < 4; ++i) {
        int c = i * 256 + tid;
        kreg[i] = *(const bf16x8*)(km + (brow + kv1 + (c >> 4)) * DIM + hc + (c & 15) * 8);
        vreg[i] = *(const bf16x8*)(vtg + vbase + (size_t)(c >> 3) * SEQ + kv1 + (c & 7) * 8);
      }
    }
    // S^T = K Q^T : A = K frag (m=kv), B = Q frag (n=q). s[nt][tm]: kv=tm*16+quad*4+r, q=l16
    fx4 s[2][4];
#pragma unroll
    for (int tm = 0; tm < 4; ++tm) {
      fx4 a0 = fx4{0.f, 0.f, 0.f, 0.f}, a1 = fx4{0.f, 0.f, 0.f, 0.f};
#pragma unroll
      for (int dc = 0; dc < 4; ++dc) {
        bf16x8 kf = *(const bf16x8*)&sm.s.Ks[tm * 16 + l16][dc * 32 + quad * 8];
        a0 = __builtin_amdgcn_mfma_f32_16x16x32_bf16(kf, aq[0][dc], a0, 0, 0, 0);
        a1 = __builtin_amdgcn_mfma_f32_16x16x32_bf16(kf, aq[1][dc], a1, 0, 0, 0);
      }
      s[0][tm] = a0 * 0.08838834764831845f;
      s[1][tm] = a1 * 0.08838834764831845f;
    }
    // causal mask (only tiles touching the diagonal)
    if (kt >= nkt - 2) {
      const int kv0 = kt * 64;
#pragma unroll
      for (int nt = 0; nt < 2; ++nt) {
        int qpos = q0 + wave * 32 + nt * 16 + l16;
#pragma unroll
        for (int tm = 0; tm < 4; ++tm)
#pragma unroll
          for (int r = 0; r < 4; ++r)
            if (kv0 + tm * 16 + quad * 4 + r > qpos) s[nt][tm][r] = -1e30f;
      }
    }
    // online softmax over kv (regs + quads); q = l16 per tile
    float alpha[2];
    bf16x4 pf[2][4];
#pragma unroll
    for (int nt = 0; nt < 2; ++nt) {
      float t = -3e38f;
#pragma unroll
      for (int tm = 0; tm < 4; ++tm)
        t = fmaxf(t, fmaxf(fmaxf(s[nt][tm][0], s[nt][tm][1]),
                           fmaxf(s[nt][tm][2], s[nt][tm][3])));
      t = fmaxf(t, __shfl_xor(t, 16));
      t = fmaxf(t, __shfl_xor(t, 32));
      float mnew = fmaxf(mr[nt], t);
      alpha[nt] = __expf(mr[nt] - mnew);
      float sum = 0.f;
#pragma unroll
      for (int tm = 0; tm < 4; ++tm) {
        fx4 p;
#pragma unroll
        for (int r = 0; r < 4; ++r) {
          p[r] = __expf(s[nt][tm][r] - mnew);
          sum += p[r];
        }
        bf16x4 pb;
        pb[0] = (short)f2bf(p[0]); pb[1] = (short)f2bf(p[1]);
        pb[2] = (short)f2bf(p[2]); pb[3] = (short)f2bf(p[3]);
        pf[nt][tm] = pb;
      }
      sum += __shfl_xor(sum, 16);
      sum += __shfl_xor(sum, 32);
      lr[nt] = lr[nt] * alpha[nt] + sum;
      mr[nt] = mnew;
      // rescale O^T tiles: col=q -> alpha is lane-uniform across all 4 regs
#pragma unroll
      for (int dt = 0; dt < 8; ++dt) o[nt][dt] *= alpha[nt];
    }
    // O^T += V^T P^T : A = V^T frag (m=d, k=kv=quad*4+j, b64), B = pf (registers!)
#pragma unroll
    for (int tm = 0; tm < 4; ++tm) {
#pragma unroll
      for (int dt = 0; dt < 8; ++dt) {
        bf16x4 vf = *(const bf16x4*)&sm.s.Vt[dt * 16 + l16][tm * 16 + quad * 4];
        o[0][dt] = __builtin_amdgcn_mfma_f32_16x16x16bf16_1k(vf, pf[0][tm], o[0][dt], 0, 0, 0);
        o[1][dt] = __builtin_amdgcn_mfma_f32_16x16x16bf16_1k(vf, pf[1][tm], o[1][dt], 0, 0, 0);
      }
    }
  }
  // epilogue: O^T -> LDS transpose (reuse tile memory) -> coalesced global
  __syncthreads();   // all waves done reading Ks/Vt
#pragma unroll
  for (int nt = 0; nt < 2; ++nt) {
    float inv = 1.f / lr[nt];
#pragma unroll
    for (int dt = 0; dt < 8; ++dt) {
      fx4 v = o[nt][dt];
      u16x4 p;
      p[0] = f2bf(v[0] * inv); p[1] = f2bf(v[1] * inv);
      p[2] = f2bf(v[2] * inv); p[3] = f2bf(v[3] * inv);
      *(u16x4*)&sm.Ot[wave][nt * 16 + l16][dt * 16 + quad * 4] = p;
    }
  }
  // wave-private region: compiler's lgkmcnt ordering suffices (no barrier)
#pragma unroll
  for (int i = 0; i < 8; ++i) {
    int c = i * 64 + lane;
    int row = c >> 4;          // 0..31
    int ch = c & 15;           // 16B chunks across 128 d
    bf16x8 t = *(const bf16x8*)&sm.Ot[wave][row][ch * 8];
    *(bf16x8*)(ao + (brow + q0 + wave * 32 + row) * DIM + hc + ch * 8) = t;
  }
}

// ---------------------------------------------------------------- launch
extern "C" void kernel_launch(void* const* d_in, const int* in_sizes, int n_in,
                              void* d_out, int out_size, void* d_ws, size_t ws_size,
                              hipStream_t stream) {
  const float* x    = (const float*)d_in[0];
  const float* fcos = (const float*)d_in[2];
  const float* fsin = (const float*)d_in[3];
  const float* wq   = (const float*)d_in[5];
  const float* wk   = (const float*)d_in[6];
  const float* wv   = (const float*)d_in[7];
  const float* wo   = (const float*)d_in[8];
  float* out = (float*)d_out;

  const size_t XN = (size_t)ROWS * DIM;
  const size_t WN = (size_t)DIM * DIM;
  u16* ws  = (u16*)d_ws;
  u16* xb  = ws;
  u16* wqb = xb + XN;
  u16* wkb = wqb + WN;
  u16* wvb = wkb + WN;
  u16* wob = wvb + WN;
  u16* q   = wob + WN;
  u16* k   = q + XN;
  u16* vtg = k + XN;   // V written pre-transposed by gemm_qkv8 (old v slot)
  u16* ao  = vtg + XN;

  const int total_chunks = (int)((XN + 4 * WN) / 4);
  cvt5_kernel<<<total_chunks / 256, 256, 0, stream>>>(x, wq, wk, wv, wo, ws);

  gemm_qkv8<<<dim3(768), 512, 0, stream>>>(xb, wqb, wkb, wvb, q, k, vtg, fcos, fsin);

  attn_kernel<<<dim3(512), 256, 0, stream>>>(q, k, vtg, ao);

  gemm_out8<<<dim3(256), 512, 0, stream>>>(ao, wob, out);
}

// Round 11
// 387.457 us; speedup vs baseline: 1.0024x; 1.0024x over previous
//
#include <hip/hip_runtime.h>
#include <stdint.h>

#define DIM 2048
#define SEQ 2048
#define NHEADS 16
#define HDIM 128
#define BSZ 2
#define ROWS (BSZ*SEQ)   // 4096

typedef uint16_t u16;
typedef __attribute__((ext_vector_type(8))) short bf16x8;
typedef __attribute__((ext_vector_type(4))) short bf16x4;
typedef __attribute__((ext_vector_type(4))) float fx4;
typedef __attribute__((ext_vector_type(4))) uint16_t u16x4;

typedef const __attribute__((address_space(1))) uint32_t* gp_t;
typedef __attribute__((address_space(3))) uint32_t* lp_t;
#define GLL16(g, l) __builtin_amdgcn_global_load_lds((gp_t)(g), (lp_t)(l), 16, 0, 0)

__device__ inline u16 f2bf(float f) {
  union { float f; uint32_t u; } v; v.f = f;
  uint32_t u = v.u;
  u += 0x7FFFu + ((u >> 16) & 1u);   // RNE
  return (u16)(u >> 16);
}
__device__ inline float bf2f(u16 h) {
  union { uint32_t u; float f; } v; v.u = ((uint32_t)h) << 16;
  return v.f;
}

// ---------------------------------------------------------------- fused convert fp32 -> bf16
__global__ __launch_bounds__(256) void cvt5_kernel(const float* __restrict__ sx,
    const float* __restrict__ s1, const float* __restrict__ s2,
    const float* __restrict__ s3, const float* __restrict__ s4,
    u16* __restrict__ dst) {
  const int XC = (ROWS * DIM) / 4;
  const int WC = (DIM * DIM) / 4;          // 2^20
  int i = blockIdx.x * 256 + threadIdx.x;
  const float* src;
  int off;
  if (i < XC) { src = sx; off = i; }
  else {
    int t = i - XC;
    int w = t >> 20;
    off = t & (WC - 1);
    src = (w == 0) ? s1 : (w == 1) ? s2 : (w == 2) ? s3 : s4;
  }
  fx4 f = *(const fx4*)(src + (size_t)off * 4);
  u16x4 o;
  o[0] = f2bf(f[0]); o[1] = f2bf(f[1]); o[2] = f2bf(f[2]); o[3] = f2bf(f[3]);
  *(u16x4*)(dst + (size_t)i * 4) = o;
}

// ---------------------------------------------------------------- QKV GEMM: 256x128 tile, 4-phase schedule
// 768 blocks = 3.0 exact rounds; r2 measured-best skeleton (sched_barrier-pinned counted
// waits, 2-half-tile prefetch, vmcnt(4) boundary), T2 swizzle, T5 setprio, T1 XCD swizzle.
// Epilogue: RoPE fused for z<2; V (z==2) written TRANSPOSED into vtg via LDS.
#define BM 256
#define BN 128
#define BK 64
#define NT (DIM / BK)         // 32
#define BUFSZ ((BM + BN) * BK) // 24576 u16 per K-tile buffer

__global__ __launch_bounds__(512, 2) void gemm_qkv8(const u16* __restrict__ A,
    const u16* __restrict__ B0, const u16* __restrict__ B1, const u16* __restrict__ B2,
    u16* __restrict__ C0, u16* __restrict__ C1, u16* __restrict__ vtg,
    const float* __restrict__ fcos, const float* __restrict__ fsin) {
  __shared__ __align__(16) u16 sm[2 * BUFSZ];   // 96 KiB

  const int tid  = threadIdx.x;
  const int lane = tid & 63, wave = tid >> 6;
  const int l16  = lane & 15, quad = lane >> 4;
  const int wm   = wave >> 2;        // 0..1 (M half: 128 rows)
  const int wn   = wave & 3;         // 0..3 (N quarter: 32 cols)

  // XCD-aware bijective swizzle over 768 blocks (96 per XCD)
  int t = (blockIdx.x & 7) * 96 + (blockIdx.x >> 3);
  const int z   = t >> 8;            // 0..2 : Q,K,V
  const int rem = t & 255;
  const int M0  = (rem >> 4) * BM;
  const int N0  = (rem & 15) * BN;
  const u16* B = (z == 0) ? B0 : (z == 1) ? B1 : B2;

  // stage-side: half-tile = 128 rows x 64 cols (16 KiB) = 2 loads/thread.
  // LDS dest LINEAR; global source chunk inverse-swizzled.
  const int u0 = tid, u1 = 512 + tid;
  const int rl0 = u0 >> 3, ch0 = (u0 & 7) ^ (rl0 & 7);
  const int rl1 = u1 >> 3, ch1 = (u1 & 7) ^ (rl1 & 7);

  // read-side: frag (row, kh) at elem row*64 + ((kh*4+quad)^(row&7))*8 ; row&7 == l16&7
  const int sw  = l16 & 7;
  const int ka0 = (quad ^ sw) * 8;          // kh=0 swizzled chunk offset (elems)
  const int ka1 = ((4 + quad) ^ sw) * 8;    // kh=1
  const int rowA = (wm * 128 + l16) * BK;   // A rows 0..255 contiguous (halves adjacent)
  const int rowB = (wn * 32  + l16) * BK;   // B rows 0..127

// stage A half-tile h (rows h*128..h*128+127) of K-tile kt2 into buf[kt2&1]
#define STGA(h, kt2) do { if ((kt2) < NT) {                                              \
    const u16* _g = A + (size_t)(M0 + (h) * 128) * DIM + (kt2) * BK;                     \
    u16* _l = sm + ((kt2) & 1) * BUFSZ + (h) * 8192 + wave * 512;                        \
    GLL16(_g + (size_t)rl0 * DIM + ch0 * 8, _l);                                         \
    GLL16(_g + (size_t)rl1 * DIM + ch1 * 8, _l + 4096); } } while (0)
// stage the single B half-tile (rows 0..127) of K-tile kt2
#define STGB(kt2) do { if ((kt2) < NT) {                                                 \
    const u16* _g = B + (size_t)N0 * DIM + (kt2) * BK;                                   \
    u16* _l = sm + ((kt2) & 1) * BUFSZ + 16384 + wave * 512;                             \
    GLL16(_g + (size_t)rl0 * DIM + ch0 * 8, _l);                                         \
    GLL16(_g + (size_t)rl1 * DIM + ch1 * 8, _l + 4096); } } while (0)

  // prologue: tile0 {B,A0,A1} + tile1 {B,A0} = 10 loads; keep last 2 half-tiles in flight
  STGB(0); STGA(0, 0); STGA(1, 0);
  STGB(1); STGA(0, 1);
  asm volatile("s_waitcnt vmcnt(4)" ::: "memory");
  __builtin_amdgcn_s_barrier();

  fx4 acc[8][2];
#pragma unroll
  for (int m = 0; m < 8; ++m)
#pragma unroll
    for (int n = 0; n < 2; ++n) acc[m][n] = fx4{0.f, 0.f, 0.f, 0.f};

  bf16x8 af[4][2], b0[2], b1[2];

  for (int kt = 0; kt < NT; ++kt) {
    const u16* Ab = sm + (kt & 1) * BUFSZ;
    const u16* Bb = Ab + 16384;

    // ---- ph0: read A-low(8) + B-n0(2); stage (kt+1).A1; MFMA m-low x n0
#pragma unroll
    for (int m = 0; m < 4; ++m) {
      af[m][0] = *(const bf16x8*)(Ab + rowA + m * (16 * BK) + ka0);
      af[m][1] = *(const bf16x8*)(Ab + rowA + m * (16 * BK) + ka1);
    }
    b0[0] = *(const bf16x8*)(Bb + rowB + ka0);
    b0[1] = *(const bf16x8*)(Bb + rowB + ka1);
    STGA(1, kt + 1);
    asm volatile("s_waitcnt lgkmcnt(8)" ::: "memory");
    __builtin_amdgcn_sched_barrier(0);
    __builtin_amdgcn_s_barrier();
    asm volatile("s_waitcnt lgkmcnt(0)" ::: "memory");
    __builtin_amdgcn_sched_barrier(0);
    __builtin_amdgcn_s_setprio(1);
#pragma unroll
    for (int m = 0; m < 4; ++m) {
      acc[m][0] = __builtin_amdgcn_mfma_f32_16x16x32_bf16(af[m][0], b0[0], acc[m][0], 0, 0, 0);
      acc[m][0] = __builtin_amdgcn_mfma_f32_16x16x32_bf16(af[m][1], b0[1], acc[m][0], 0, 0, 0);
    }
    __builtin_amdgcn_s_setprio(0);
    __builtin_amdgcn_s_barrier();

    // ---- ph1: read B-n1(2); MFMA m-low x n1
    b1[0] = *(const bf16x8*)(Bb + rowB + 16 * BK + ka0);
    b1[1] = *(const bf16x8*)(Bb + rowB + 16 * BK + ka1);
    __builtin_amdgcn_s_barrier();
    asm volatile("s_waitcnt lgkmcnt(0)" ::: "memory");
    __builtin_amdgcn_sched_barrier(0);
    __builtin_amdgcn_s_setprio(1);
#pragma unroll
    for (int m = 0; m < 4; ++m) {
      acc[m][1] = __builtin_amdgcn_mfma_f32_16x16x32_bf16(af[m][0], b1[0], acc[m][1], 0, 0, 0);
      acc[m][1] = __builtin_amdgcn_mfma_f32_16x16x32_bf16(af[m][1], b1[1], acc[m][1], 0, 0, 0);
    }
    __builtin_amdgcn_s_setprio(0);
    __builtin_amdgcn_s_barrier();

    // ---- ph2: read A-high(8); stage (kt+2).B (B reads of this tile finished in ph1);
    //          MFMA m-high x n1
#pragma unroll
    for (int m = 0; m < 4; ++m) {
      af[m][0] = *(const bf16x8*)(Ab + rowA + (m + 4) * (16 * BK) + ka0);
      af[m][1] = *(const bf16x8*)(Ab + rowA + (m + 4) * (16 * BK) + ka1);
    }
    STGB(kt + 2);
    __builtin_amdgcn_s_barrier();
    asm volatile("s_waitcnt lgkmcnt(0)" ::: "memory");
    __builtin_amdgcn_sched_barrier(0);
    __builtin_amdgcn_s_setprio(1);
#pragma unroll
    for (int m = 0; m < 4; ++m) {
      acc[m + 4][1] = __builtin_amdgcn_mfma_f32_16x16x32_bf16(af[m][0], b1[0], acc[m + 4][1], 0, 0, 0);
      acc[m + 4][1] = __builtin_amdgcn_mfma_f32_16x16x32_bf16(af[m][1], b1[1], acc[m + 4][1], 0, 0, 0);
    }
    __builtin_amdgcn_s_setprio(0);
    __builtin_amdgcn_s_barrier();

    // ---- ph3: no ds-reads (b0 in regs); stage (kt+2).A0 (A reads finished in ph2);
    //          MFMA m-high x n0; boundary vmcnt + barrier
    STGA(0, kt + 2);
    __builtin_amdgcn_s_barrier();
    __builtin_amdgcn_s_setprio(1);
#pragma unroll
    for (int m = 0; m < 4; ++m) {
      acc[m + 4][0] = __builtin_amdgcn_mfma_f32_16x16x32_bf16(af[m][0], b0[0], acc[m + 4][0], 0, 0, 0);
      acc[m + 4][0] = __builtin_amdgcn_mfma_f32_16x16x32_bf16(af[m][1], b0[1], acc[m + 4][0], 0, 0, 0);
    }
    __builtin_amdgcn_s_setprio(0);
    // tile kt+1 fully staged when <= 2 half-tiles (= (kt+2).B/A0) outstanding
    if (kt < NT - 2) asm volatile("s_waitcnt vmcnt(4)" ::: "memory");
    else             asm volatile("s_waitcnt vmcnt(0)" ::: "memory");
    __builtin_amdgcn_sched_barrier(0);
    __builtin_amdgcn_s_barrier();
  }
#undef STGA
#undef STGB

  if (z < 2) {
    // epilogue Q/K: C[row=quad*4+r][col=l16] per 16x16 tile with fused RoPE.
    // Adjacent head-features (2p,2p+1) sit in adjacent lanes -> shfl_xor(.,1).
    u16* C = (z == 0) ? C0 : C1;
    u16* Cr = C + (size_t)(M0 + wm * 128 + quad * 4) * DIM + N0 + wn * 32 + l16;
#pragma unroll
    for (int mt = 0; mt < 8; ++mt)
#pragma unroll
      for (int r = 0; r < 4; ++r) {
        int s = (M0 + wm * 128 + mt * 16 + quad * 4 + r) & (SEQ - 1);
        const float* cb = fcos + s * 64;
        const float* sb = fsin + s * 64;
#pragma unroll
        for (int nt = 0; nt < 2; ++nt) {
          int p = (wn * 32 + nt * 16 + l16) >> 1;   // N0 multiple of 128 -> head-local
          float val = acc[mt][nt][r];
          float par = __shfl_xor(val, 1);
          float c = cb[p], sn = sb[p];
          float out = (l16 & 1) ? (par * sn + val * c) : (val * c - par * sn);
          Cr[(size_t)(mt * 16 + r) * DIM + nt * 16] = f2bf(out);
        }
      }
  } else {
    // epilogue V: transpose through LDS (staging buffers dead), write vtg[bh][d][s].
    // Tile = 256 s-rows x 128 d-cols = exactly one head. T[128 cols][256 rows] = 64 KB.
    u16 (*T)[256] = reinterpret_cast<u16 (*)[256]>(sm);
    __syncthreads();   // all waves past their last staging-buffer access
#pragma unroll
    for (int mt = 0; mt < 8; ++mt)
#pragma unroll
      for (int nt = 0; nt < 2; ++nt) {
        int col = wn * 32 + nt * 16 + l16;          // d within head: 0..127
        int rowb = (wm * 128 + mt * 16 + quad * 4) ^ ((col & 7) << 3);
        u16x4 p;
        p[0] = f2bf(acc[mt][nt][0]); p[1] = f2bf(acc[mt][nt][1]);
        p[2] = f2bf(acc[mt][nt][2]); p[3] = f2bf(acc[mt][nt][3]);
        *(u16x4*)&T[col][rowb] = p;
      }
    __syncthreads();
    const int b  = M0 >> 11;             // batch
    const int s0 = M0 & (SEQ - 1);
    const int h  = N0 >> 7;              // single head this tile covers
#pragma unroll
    for (int i = 0; i < 8; ++i) {
      int c = i * 512 + tid;             // 4096 16B chunks
      int col = c >> 5;                  // d: 0..127
      int s8 = (c & 31) * 8;             // s offset 0..248
      bf16x8 v8 = *(const bf16x8*)&T[col][s8 ^ ((col & 7) << 3)];
      *(bf16x8*)(vtg + ((size_t)(b * NHEADS + h) * HDIM + col) * SEQ + s0 + s8) = v8;
    }
  }
}

// ---------------------------------------------------------------- output GEMM: same 256x128
// 4-phase structure (duplicated verbatim from gemm_qkv8). 256 blocks = 1.0 rounds. f32 epilogue.
__global__ __launch_bounds__(512, 2) void gemm_out8(const u16* __restrict__ A,
                                                    const u16* __restrict__ B,
                                                    float* __restrict__ C) {
  __shared__ __align__(16) u16 sm[2 * BUFSZ];   // 96 KiB

  const int tid  = threadIdx.x;
  const int lane = tid & 63, wave = tid >> 6;
  const int l16  = lane & 15, quad = lane >> 4;
  const int wm   = wave >> 2;
  const int wn   = wave & 3;

  // XCD-aware bijective swizzle over 256 blocks (32 per XCD)
  int t = (blockIdx.x & 7) * 32 + (blockIdx.x >> 3);
  const int M0  = (t >> 4) * BM;
  const int N0  = (t & 15) * BN;

  const int u0 = tid, u1 = 512 + tid;
  const int rl0 = u0 >> 3, ch0 = (u0 & 7) ^ (rl0 & 7);
  const int rl1 = u1 >> 3, ch1 = (u1 & 7) ^ (rl1 & 7);

  const int sw  = l16 & 7;
  const int ka0 = (quad ^ sw) * 8;
  const int ka1 = ((4 + quad) ^ sw) * 8;
  const int rowA = (wm * 128 + l16) * BK;
  const int rowB = (wn * 32  + l16) * BK;

#define STGA(h, kt2) do { if ((kt2) < NT) {                                              \
    const u16* _g = A + (size_t)(M0 + (h) * 128) * DIM + (kt2) * BK;                     \
    u16* _l = sm + ((kt2) & 1) * BUFSZ + (h) * 8192 + wave * 512;                        \
    GLL16(_g + (size_t)rl0 * DIM + ch0 * 8, _l);                                         \
    GLL16(_g + (size_t)rl1 * DIM + ch1 * 8, _l + 4096); } } while (0)
#define STGB(kt2) do { if ((kt2) < NT) {                                                 \
    const u16* _g = B + (size_t)N0 * DIM + (kt2) * BK;                                   \
    u16* _l = sm + ((kt2) & 1) * BUFSZ + 16384 + wave * 512;                             \
    GLL16(_g + (size_t)rl0 * DIM + ch0 * 8, _l);                                         \
    GLL16(_g + (size_t)rl1 * DIM + ch1 * 8, _l + 4096); } } while (0)

  STGB(0); STGA(0, 0); STGA(1, 0);
  STGB(1); STGA(0, 1);
  asm volatile("s_waitcnt vmcnt(4)" ::: "memory");
  __builtin_amdgcn_s_barrier();

  fx4 acc[8][2];
#pragma unroll
  for (int m = 0; m < 8; ++m)
#pragma unroll
    for (int n = 0; n < 2; ++n) acc[m][n] = fx4{0.f, 0.f, 0.f, 0.f};

  bf16x8 af[4][2], b0[2], b1[2];

  for (int kt = 0; kt < NT; ++kt) {
    const u16* Ab = sm + (kt & 1) * BUFSZ;
    const u16* Bb = Ab + 16384;

    // ---- ph0
#pragma unroll
    for (int m = 0; m < 4; ++m) {
      af[m][0] = *(const bf16x8*)(Ab + rowA + m * (16 * BK) + ka0);
      af[m][1] = *(const bf16x8*)(Ab + rowA + m * (16 * BK) + ka1);
    }
    b0[0] = *(const bf16x8*)(Bb + rowB + ka0);
    b0[1] = *(const bf16x8*)(Bb + rowB + ka1);
    STGA(1, kt + 1);
    asm volatile("s_waitcnt lgkmcnt(8)" ::: "memory");
    __builtin_amdgcn_sched_barrier(0);
    __builtin_amdgcn_s_barrier();
    asm volatile("s_waitcnt lgkmcnt(0)" ::: "memory");
    __builtin_amdgcn_sched_barrier(0);
    __builtin_amdgcn_s_setprio(1);
#pragma unroll
    for (int m = 0; m < 4; ++m) {
      acc[m][0] = __builtin_amdgcn_mfma_f32_16x16x32_bf16(af[m][0], b0[0], acc[m][0], 0, 0, 0);
      acc[m][0] = __builtin_amdgcn_mfma_f32_16x16x32_bf16(af[m][1], b0[1], acc[m][0], 0, 0, 0);
    }
    __builtin_amdgcn_s_setprio(0);
    __builtin_amdgcn_s_barrier();

    // ---- ph1
    b1[0] = *(const bf16x8*)(Bb + rowB + 16 * BK + ka0);
    b1[1] = *(const bf16x8*)(Bb + rowB + 16 * BK + ka1);
    __builtin_amdgcn_s_barrier();
    asm volatile("s_waitcnt lgkmcnt(0)" ::: "memory");
    __builtin_amdgcn_sched_barrier(0);
    __builtin_amdgcn_s_setprio(1);
#pragma unroll
    for (int m = 0; m < 4; ++m) {
      acc[m][1] = __builtin_amdgcn_mfma_f32_16x16x32_bf16(af[m][0], b1[0], acc[m][1], 0, 0, 0);
      acc[m][1] = __builtin_amdgcn_mfma_f32_16x16x32_bf16(af[m][1], b1[1], acc[m][1], 0, 0, 0);
    }
    __builtin_amdgcn_s_setprio(0);
    __builtin_amdgcn_s_barrier();

    // ---- ph2
#pragma unroll
    for (int m = 0; m < 4; ++m) {
      af[m][0] = *(const bf16x8*)(Ab + rowA + (m + 4) * (16 * BK) + ka0);
      af[m][1] = *(const bf16x8*)(Ab + rowA + (m + 4) * (16 * BK) + ka1);
    }
    STGB(kt + 2);
    __builtin_amdgcn_s_barrier();
    asm volatile("s_waitcnt lgkmcnt(0)" ::: "memory");
    __builtin_amdgcn_sched_barrier(0);
    __builtin_amdgcn_s_setprio(1);
#pragma unroll
    for (int m = 0; m < 4; ++m) {
      acc[m + 4][1] = __builtin_amdgcn_mfma_f32_16x16x32_bf16(af[m][0], b1[0], acc[m + 4][1], 0, 0, 0);
      acc[m + 4][1] = __builtin_amdgcn_mfma_f32_16x16x32_bf16(af[m][1], b1[1], acc[m + 4][1], 0, 0, 0);
    }
    __builtin_amdgcn_s_setprio(0);
    __builtin_amdgcn_s_barrier();

    // ---- ph3
    STGA(0, kt + 2);
    __builtin_amdgcn_s_barrier();
    __builtin_amdgcn_s_setprio(1);
#pragma unroll
    for (int m = 0; m < 4; ++m) {
      acc[m + 4][0] = __builtin_amdgcn_mfma_f32_16x16x32_bf16(af[m][0], b0[0], acc[m + 4][0], 0, 0, 0);
      acc[m + 4][0] = __builtin_amdgcn_mfma_f32_16x16x32_bf16(af[m][1], b0[1], acc[m + 4][0], 0, 0, 0);
    }
    __builtin_amdgcn_s_setprio(0);
    if (kt < NT - 2) asm volatile("s_waitcnt vmcnt(4)" ::: "memory");
    else             asm volatile("s_waitcnt vmcnt(0)" ::: "memory");
    __builtin_amdgcn_sched_barrier(0);
    __builtin_amdgcn_s_barrier();
  }
#undef STGA
#undef STGB

  // epilogue: f32 C[row=quad*4+r][col=l16] per 16x16 tile
  float* Cr = C + (size_t)(M0 + wm * 128 + quad * 4) * DIM + N0 + wn * 32 + l16;
#pragma unroll
  for (int mt = 0; mt < 8; ++mt)
#pragma unroll
    for (int nt = 0; nt < 2; ++nt)
#pragma unroll
      for (int r = 0; r < 4; ++r)
        Cr[(size_t)(mt * 16 + r) * DIM + nt * 16] = acc[mt][nt][r];
}

// ---------------------------------------------------------------- flash attention, S^T form
// Double-buffered K/V LDS: ONE __syncthreads per K-tile (was 2). Step kt: store tile kt+1
// (regs, loaded in step kt-1) into buf[cur^1] (last read in step kt-1, sealed by its end
// barrier); issue tile kt+2 global loads (hide under compute); compute on buf[cur]; barrier.
// Defer-max (T13): skip alpha/rescale when __all(t - mr <= 8); P bounded by e^8 (bf16-safe).
// Fully-masked final-tile rows: skip keeps mr finite -> P = exp(-1e30 - mr) = 0, correct.
struct SMemS { u16 Ks[2][64][136]; u16 Vt[2][128][72]; };
union SMemU { SMemS s; u16 Ot[4][32][136]; };

__global__ __launch_bounds__(256, 2) void attn_kernel(const u16* __restrict__ qm,
                                                      const u16* __restrict__ km,
                                                      const u16* __restrict__ vtg,
                                                      u16* __restrict__ ao) {
  __shared__ __align__(16) SMemU sm;
  const int tid = threadIdx.x;
  const int lane = tid & 63, wave = tid >> 6;
  const int l16 = lane & 15, quad = lane >> 4;
  const int idx = blockIdx.x;
  const int bh = idx & 31;
  const int j = idx >> 5;
  const int qt = (j < 8) ? (15 - j) : (j - 8);   // complementary pairing
  const int b = bh >> 4, h = bh & 15;
  const int q0 = qt * 128;
  const size_t brow = (size_t)b * SEQ;
  const int hc = h * HDIM;
  const size_t vbase = (size_t)bh * HDIM * SEQ;
  const int nkt = 2 * qt + 2;

  // Q as B-operand frags: B[n=q=l16][k=d=quad*8+j]
  bf16x8 aq[2][4];
#pragma unroll
  for (int nt = 0; nt < 2; ++nt) {
    size_t qbase = (brow + q0 + wave * 32 + nt * 16 + l16) * DIM + hc;
#pragma unroll
    for (int dc = 0; dc < 4; ++dc)
      aq[nt][dc] = *(const bf16x8*)(qm + qbase + dc * 32 + quad * 8);
  }
  fx4 o[2][8];   // O^T tiles: [q-tile][d-tile], C-layout col=q=l16, row=d=quad*4+r
#pragma unroll
  for (int nt = 0; nt < 2; ++nt)
#pragma unroll
    for (int dt = 0; dt < 8; ++dt) o[nt][dt] = fx4{0.f, 0.f, 0.f, 0.f};
  float mr[2] = {-3e38f, -3e38f}, lr[2] = {0.f, 0.f};   // per-lane: q = l16 of each tile

  bf16x8 kreg[4], vreg[4];
  // tile 0 -> regs -> buf0
#pragma unroll
  for (int i = 0; i < 4; ++i) {
    int c = i * 256 + tid;
    kreg[i] = *(const bf16x8*)(km + (brow + (c >> 4)) * DIM + hc + (c & 15) * 8);
    vreg[i] = *(const bf16x8*)(vtg + vbase + (size_t)(c >> 3) * SEQ + (c & 7) * 8);
  }
#pragma unroll
  for (int i = 0; i < 4; ++i) {
    int c = i * 256 + tid;
    *(bf16x8*)&sm.s.Ks[0][c >> 4][(c & 15) * 8] = kreg[i];
    *(bf16x8*)&sm.s.Vt[0][c >> 3][(c & 7) * 8] = vreg[i];
  }
  // tile 1 -> regs (issue early)
  if (1 < nkt) {
#pragma unroll
    for (int i = 0; i < 4; ++i) {
      int c = i * 256 + tid;
      kreg[i] = *(const bf16x8*)(km + (brow + 64 + (c >> 4)) * DIM + hc + (c & 15) * 8);
      vreg[i] = *(const bf16x8*)(vtg + vbase + (size_t)(c >> 3) * SEQ + 64 + (c & 7) * 8);
    }
  }
  __syncthreads();

  for (int kt = 0; kt < nkt; ++kt) {
    const int cur = kt & 1;
    // store tile kt+1 into the other buffer (its last readers finished at prev barrier)
    if (kt + 1 < nkt) {
#pragma unroll
      for (int i = 0; i < 4; ++i) {
        int c = i * 256 + tid;
        *(bf16x8*)&sm.s.Ks[cur ^ 1][c >> 4][(c & 15) * 8] = kreg[i];
        *(bf16x8*)&sm.s.Vt[cur ^ 1][c >> 3][(c & 7) * 8] = vreg[i];
      }
    }
    // issue tile kt+2 global loads (HBM latency hides under compute below)
    if (kt + 2 < nkt) {
      const int kv2 = (kt + 2) * 64;
#pragma unroll
      for (int i = 0; i < 4; ++i) {
        int c = i * 256 + tid;
        kreg[i] = *(const bf16x8*)(km + (brow + kv2 + (c >> 4)) * DIM + hc + (c & 15) * 8);
        vreg[i] = *(const bf16x8*)(vtg + vbase + (size_t)(c >> 3) * SEQ + kv2 + (c & 7) * 8);
      }
    }
    // S^T = K Q^T : A = K frag (m=kv), B = Q frag (n=q). s[nt][tm]: kv=tm*16+quad*4+r, q=l16
    fx4 s[2][4];
#pragma unroll
    for (int tm = 0; tm < 4; ++tm) {
      fx4 a0 = fx4{0.f, 0.f, 0.f, 0.f}, a1 = fx4{0.f, 0.f, 0.f, 0.f};
#pragma unroll
      for (int dc = 0; dc < 4; ++dc) {
        bf16x8 kf = *(const bf16x8*)&sm.s.Ks[cur][tm * 16 + l16][dc * 32 + quad * 8];
        a0 = __builtin_amdgcn_mfma_f32_16x16x32_bf16(kf, aq[0][dc], a0, 0, 0, 0);
        a1 = __builtin_amdgcn_mfma_f32_16x16x32_bf16(kf, aq[1][dc], a1, 0, 0, 0);
      }
      s[0][tm] = a0 * 0.08838834764831845f;
      s[1][tm] = a1 * 0.08838834764831845f;
    }
    // causal mask (only tiles touching the diagonal)
    if (kt >= nkt - 2) {
      const int kv0 = kt * 64;
#pragma unroll
      for (int nt = 0; nt < 2; ++nt) {
        int qpos = q0 + wave * 32 + nt * 16 + l16;
#pragma unroll
        for (int tm = 0; tm < 4; ++tm)
#pragma unroll
          for (int r = 0; r < 4; ++r)
            if (kv0 + tm * 16 + quad * 4 + r > qpos) s[nt][tm][r] = -1e30f;
      }
    }
    // online softmax over kv (regs + quads); q = l16 per tile; defer-max (T13)
    bf16x4 pf[2][4];
#pragma unroll
    for (int nt = 0; nt < 2; ++nt) {
      float t = -3e38f;
#pragma unroll
      for (int tm = 0; tm < 4; ++tm)
        t = fmaxf(t, fmaxf(fmaxf(s[nt][tm][0], s[nt][tm][1]),
                           fmaxf(s[nt][tm][2], s[nt][tm][3])));
      t = fmaxf(t, __shfl_xor(t, 16));
      t = fmaxf(t, __shfl_xor(t, 32));
      if (!__all(t - mr[nt] <= 8.f)) {
        float mnew = fmaxf(mr[nt], t);
        float alpha = __expf(mr[nt] - mnew);
        lr[nt] *= alpha;
        mr[nt] = mnew;
#pragma unroll
        for (int dt = 0; dt < 8; ++dt) o[nt][dt] *= alpha;
      }
      float sum = 0.f;
#pragma unroll
      for (int tm = 0; tm < 4; ++tm) {
        fx4 p;
#pragma unroll
        for (int r = 0; r < 4; ++r) {
          p[r] = __expf(s[nt][tm][r] - mr[nt]);
          sum += p[r];
        }
        bf16x4 pb;
        pb[0] = (short)f2bf(p[0]); pb[1] = (short)f2bf(p[1]);
        pb[2] = (short)f2bf(p[2]); pb[3] = (short)f2bf(p[3]);
        pf[nt][tm] = pb;
      }
      sum += __shfl_xor(sum, 16);
      sum += __shfl_xor(sum, 32);
      lr[nt] += sum;
    }
    // O^T += V^T P^T : A = V^T frag (m=d, k=kv=quad*4+j, b64), B = pf (registers!)
#pragma unroll
    for (int tm = 0; tm < 4; ++tm) {
#pragma unroll
      for (int dt = 0; dt < 8; ++dt) {
        bf16x4 vf = *(const bf16x4*)&sm.s.Vt[cur][dt * 16 + l16][tm * 16 + quad * 4];
        o[0][dt] = __builtin_amdgcn_mfma_f32_16x16x16bf16_1k(vf, pf[0][tm], o[0][dt], 0, 0, 0);
        o[1][dt] = __builtin_amdgcn_mfma_f32_16x16x16bf16_1k(vf, pf[1][tm], o[1][dt], 0, 0, 0);
      }
    }
    __syncthreads();   // seal this step's reads and tile-(kt+1) writes
  }
  // epilogue: O^T -> LDS transpose (reuse tile memory) -> coalesced global
#pragma unroll
  for (int nt = 0; nt < 2; ++nt) {
    float inv = 1.f / lr[nt];
#pragma unroll
    for (int dt = 0; dt < 8; ++dt) {
      fx4 v = o[nt][dt];
      u16x4 p;
      p[0] = f2bf(v[0] * inv); p[1] = f2bf(v[1] * inv);
      p[2] = f2bf(v[2] * inv); p[3] = f2bf(v[3] * inv);
      *(u16x4*)&sm.Ot[wave][nt * 16 + l16][dt * 16 + quad * 4] = p;
    }
  }
  // wave-private region: compiler's lgkmcnt ordering suffices (no barrier)
#pragma unroll
  for (int i = 0; i < 8; ++i) {
    int c = i * 64 + lane;
    int row = c >> 4;          // 0..31
    int ch = c & 15;           // 16B chunks across 128 d
    bf16x8 t = *(const bf16x8*)&sm.Ot[wave][row][ch * 8];
    *(bf16x8*)(ao + (brow + q0 + wave * 32 + row) * DIM + hc + ch * 8) = t;
  }
}

// ---------------------------------------------------------------- launch
extern "C" void kernel_launch(void* const* d_in, const int* in_sizes, int n_in,
                              void* d_out, int out_size, void* d_ws, size_t ws_size,
                              hipStream_t stream) {
  const float* x    = (const float*)d_in[0];
  const float* fcos = (const float*)d_in[2];
  const float* fsin = (const float*)d_in[3];
  const float* wq   = (const float*)d_in[5];
  const float* wk   = (const float*)d_in[6];
  const float* wv   = (const float*)d_in[7];
  const float* wo   = (const float*)d_in[8];
  float* out = (float*)d_out;

  const size_t XN = (size_t)ROWS * DIM;
  const size_t WN = (size_t)DIM * DIM;
  u16* ws  = (u16*)d_ws;
  u16* xb  = ws;
  u16* wqb = xb + XN;
  u16* wkb = wqb + WN;
  u16* wvb = wkb + WN;
  u16* wob = wvb + WN;
  u16* q   = wob + WN;
  u16* k   = q + XN;
  u16* vtg = k + XN;   // V written pre-transposed by gemm_qkv8 (old v slot)
  u16* ao  = vtg + XN;

  const int total_chunks = (int)((XN + 4 * WN) / 4);
  cvt5_kernel<<<total_chunks / 256, 256, 0, stream>>>(x, wq, wk, wv, wo, ws);

  gemm_qkv8<<<dim3(768), 512, 0, stream>>>(xb, wqb, wkb, wvb, q, k, vtg, fcos, fsin);

  attn_kernel<<<dim3(512), 256, 0, stream>>>(q, k, vtg, ao);

  gemm_out8<<<dim3(256), 512, 0, stream>>>(ao, wob, out);
}

// Round 13
// 381.563 us; speedup vs baseline: 1.0179x; 1.0154x over previous
//
#include <hip/hip_runtime.h>
#include <stdint.h>

#define DIM 2048
#define SEQ 2048
#define NHEADS 16
#define HDIM 128
#define BSZ 2
#define ROWS (BSZ*SEQ)   // 4096

typedef uint16_t u16;
typedef __attribute__((ext_vector_type(8))) short bf16x8;
typedef __attribute__((ext_vector_type(4))) short bf16x4;
typedef __attribute__((ext_vector_type(4))) float fx4;
typedef __attribute__((ext_vector_type(4))) uint16_t u16x4;

typedef const __attribute__((address_space(1))) uint32_t* gp_t;
typedef __attribute__((address_space(3))) uint32_t* lp_t;
#define GLL16(g, l) __builtin_amdgcn_global_load_lds((gp_t)(g), (lp_t)(l), 16, 0, 0)

__device__ inline u16 f2bf(float f) {
  union { float f; uint32_t u; } v; v.f = f;
  uint32_t u = v.u;
  u += 0x7FFFu + ((u >> 16) & 1u);   // RNE
  return (u16)(u >> 16);
}
__device__ inline float bf2f(u16 h) {
  union { uint32_t u; float f; } v; v.u = ((uint32_t)h) << 16;
  return v.f;
}

// ---------------------------------------------------------------- fused convert fp32 -> bf16
__global__ __launch_bounds__(256) void cvt5_kernel(const float* __restrict__ sx,
    const float* __restrict__ s1, const float* __restrict__ s2,
    const float* __restrict__ s3, const float* __restrict__ s4,
    u16* __restrict__ dst) {
  const int XC = (ROWS * DIM) / 4;
  const int WC = (DIM * DIM) / 4;          // 2^20
  int i = blockIdx.x * 256 + threadIdx.x;
  const float* src;
  int off;
  if (i < XC) { src = sx; off = i; }
  else {
    int t = i - XC;
    int w = t >> 20;
    off = t & (WC - 1);
    src = (w == 0) ? s1 : (w == 1) ? s2 : (w == 2) ? s3 : s4;
  }
  fx4 f = *(const fx4*)(src + (size_t)off * 4);
  u16x4 o;
  o[0] = f2bf(f[0]); o[1] = f2bf(f[1]); o[2] = f2bf(f[2]); o[3] = f2bf(f[3]);
  *(u16x4*)(dst + (size_t)i * 4) = o;
}

// ---------------------------------------------------------------- QKV GEMM: 256x128 tile, 2-phase schedule
// RACE-FIXED 2-phase: ALL ds_reads in ph0 (16 A-frags + 4 B-frags), sealed by ph0's
// lgkmcnt(0) before the ph0-end barrier. ph1 has ZERO ds_reads: stages B(kt+2)+A0(kt+2)
// into buf[cur] (every wave sealed its buf[cur] reads before the barrier ph1 follows),
// MFMA m-high from registers. 3 barriers per kt for 32 MFMA (r9: 8). Boundary vmcnt(4):
// per-kt +6 loads, 4 newest (= ph1's B/A0 of kt+2) may remain in flight. 768 blocks =
// 3.0 exact rounds. Epilogue: RoPE fused for z<2; V (z==2) written TRANSPOSED into vtg.
#define BM 256
#define BN 128
#define BK 64
#define NT (DIM / BK)         // 32
#define BUFSZ ((BM + BN) * BK) // 24576 u16 per K-tile buffer

__global__ __launch_bounds__(512, 2) void gemm_qkv8(const u16* __restrict__ A,
    const u16* __restrict__ B0, const u16* __restrict__ B1, const u16* __restrict__ B2,
    u16* __restrict__ C0, u16* __restrict__ C1, u16* __restrict__ vtg,
    const float* __restrict__ fcos, const float* __restrict__ fsin) {
  __shared__ __align__(16) u16 sm[2 * BUFSZ];   // 96 KiB

  const int tid  = threadIdx.x;
  const int lane = tid & 63, wave = tid >> 6;
  const int l16  = lane & 15, quad = lane >> 4;
  const int wm   = wave >> 2;        // 0..1 (M half: 128 rows)
  const int wn   = wave & 3;         // 0..3 (N quarter: 32 cols)

  // XCD-aware bijective swizzle over 768 blocks (96 per XCD)
  int t = (blockIdx.x & 7) * 96 + (blockIdx.x >> 3);
  const int z   = t >> 8;            // 0..2 : Q,K,V
  const int rem = t & 255;
  const int M0  = (rem >> 4) * BM;
  const int N0  = (rem & 15) * BN;
  const u16* B = (z == 0) ? B0 : (z == 1) ? B1 : B2;

  // stage-side: half-tile = 128 rows x 64 cols (16 KiB) = 2 loads/thread.
  const int u0 = tid, u1 = 512 + tid;
  const int rl0 = u0 >> 3, ch0 = (u0 & 7) ^ (rl0 & 7);
  const int rl1 = u1 >> 3, ch1 = (u1 & 7) ^ (rl1 & 7);

  // read-side: frag (row, kh) at elem row*64 + ((kh*4+quad)^(row&7))*8 ; row&7 == l16&7
  const int sw  = l16 & 7;
  const int ka0 = (quad ^ sw) * 8;          // kh=0 swizzled chunk offset (elems)
  const int ka1 = ((4 + quad) ^ sw) * 8;    // kh=1
  const int rowA = (wm * 128 + l16) * BK;
  const int rowB = (wn * 32  + l16) * BK;

#define STGA(h, kt2) do { if ((kt2) < NT) {                                              \
    const u16* _g = A + (size_t)(M0 + (h) * 128) * DIM + (kt2) * BK;                     \
    u16* _l = sm + ((kt2) & 1) * BUFSZ + (h) * 8192 + wave * 512;                        \
    GLL16(_g + (size_t)rl0 * DIM + ch0 * 8, _l);                                         \
    GLL16(_g + (size_t)rl1 * DIM + ch1 * 8, _l + 4096); } } while (0)
#define STGB(kt2) do { if ((kt2) < NT) {                                                 \
    const u16* _g = B + (size_t)N0 * DIM + (kt2) * BK;                                   \
    u16* _l = sm + ((kt2) & 1) * BUFSZ + 16384 + wave * 512;                             \
    GLL16(_g + (size_t)rl0 * DIM + ch0 * 8, _l);                                         \
    GLL16(_g + (size_t)rl1 * DIM + ch1 * 8, _l + 4096); } } while (0)

  // prologue: tile0 {B,A0,A1} + tile1 {B,A0} = 10 loads; keep last 2 half-tiles in flight
  STGB(0); STGA(0, 0); STGA(1, 0);
  STGB(1); STGA(0, 1);
  asm volatile("s_waitcnt vmcnt(4)" ::: "memory");
  __builtin_amdgcn_s_barrier();

  fx4 acc[8][2];
#pragma unroll
  for (int m = 0; m < 8; ++m)
#pragma unroll
    for (int n = 0; n < 2; ++n) acc[m][n] = fx4{0.f, 0.f, 0.f, 0.f};

  bf16x8 af[8][2], b0[2], b1[2];

  for (int kt = 0; kt < NT; ++kt) {
    const u16* Ab = sm + (kt & 1) * BUFSZ;
    const u16* Bb = Ab + 16384;

    // ---- ph0: read ALL A(16) + B(4); stage (kt+1).A1 (other buffer, sealed long ago);
    //          lgkmcnt(0) seals EVERY buf[cur] read before end barrier; MFMA m-low
#pragma unroll
    for (int m = 0; m < 8; ++m) {
      af[m][0] = *(const bf16x8*)(Ab + rowA + m * (16 * BK) + ka0);
      af[m][1] = *(const bf16x8*)(Ab + rowA + m * (16 * BK) + ka1);
    }
    b0[0] = *(const bf16x8*)(Bb + rowB + ka0);
    b0[1] = *(const bf16x8*)(Bb + rowB + ka1);
    b1[0] = *(const bf16x8*)(Bb + rowB + 16 * BK + ka0);
    b1[1] = *(const bf16x8*)(Bb + rowB + 16 * BK + ka1);
    STGA(1, kt + 1);
    asm volatile("s_waitcnt lgkmcnt(8)" ::: "memory");
    __builtin_amdgcn_sched_barrier(0);
    __builtin_amdgcn_s_barrier();
    asm volatile("s_waitcnt lgkmcnt(0)" ::: "memory");
    __builtin_amdgcn_sched_barrier(0);
    __builtin_amdgcn_s_setprio(1);
#pragma unroll
    for (int m = 0; m < 4; ++m) {
      acc[m][0] = __builtin_amdgcn_mfma_f32_16x16x32_bf16(af[m][0], b0[0], acc[m][0], 0, 0, 0);
      acc[m][0] = __builtin_amdgcn_mfma_f32_16x16x32_bf16(af[m][1], b0[1], acc[m][0], 0, 0, 0);
      acc[m][1] = __builtin_amdgcn_mfma_f32_16x16x32_bf16(af[m][0], b1[0], acc[m][1], 0, 0, 0);
      acc[m][1] = __builtin_amdgcn_mfma_f32_16x16x32_bf16(af[m][1], b1[1], acc[m][1], 0, 0, 0);
    }
    __builtin_amdgcn_s_setprio(0);
    __builtin_amdgcn_s_barrier();

    // ---- ph1: NO ds-reads; stage (kt+2).B + (kt+2).A0 into buf[cur] (all reads sealed
    //          by ph0's lgkmcnt(0) before the barrier we just crossed); MFMA m-high from
    //          registers; boundary vmcnt + barrier
    STGB(kt + 2);
    STGA(0, kt + 2);
    __builtin_amdgcn_s_setprio(1);
#pragma unroll
    for (int m = 0; m < 4; ++m) {
      acc[m + 4][0] = __builtin_amdgcn_mfma_f32_16x16x32_bf16(af[m + 4][0], b0[0], acc[m + 4][0], 0, 0, 0);
      acc[m + 4][0] = __builtin_amdgcn_mfma_f32_16x16x32_bf16(af[m + 4][1], b0[1], acc[m + 4][0], 0, 0, 0);
      acc[m + 4][1] = __builtin_amdgcn_mfma_f32_16x16x32_bf16(af[m + 4][0], b1[0], acc[m + 4][1], 0, 0, 0);
      acc[m + 4][1] = __builtin_amdgcn_mfma_f32_16x16x32_bf16(af[m + 4][1], b1[1], acc[m + 4][1], 0, 0, 0);
    }
    __builtin_amdgcn_s_setprio(0);
    // tile kt+1 fully staged when <= 4 newest (= (kt+2).B/A0) outstanding
    if (kt < NT - 2) asm volatile("s_waitcnt vmcnt(4)" ::: "memory");
    else             asm volatile("s_waitcnt vmcnt(0)" ::: "memory");
    __builtin_amdgcn_sched_barrier(0);
    __builtin_amdgcn_s_barrier();
  }
#undef STGA
#undef STGB

  if (z < 2) {
    // epilogue Q/K: C[row=quad*4+r][col=l16] per 16x16 tile with fused RoPE.
    u16* C = (z == 0) ? C0 : C1;
    u16* Cr = C + (size_t)(M0 + wm * 128 + quad * 4) * DIM + N0 + wn * 32 + l16;
#pragma unroll
    for (int mt = 0; mt < 8; ++mt)
#pragma unroll
      for (int r = 0; r < 4; ++r) {
        int s = (M0 + wm * 128 + mt * 16 + quad * 4 + r) & (SEQ - 1);
        const float* cb = fcos + s * 64;
        const float* sb = fsin + s * 64;
#pragma unroll
        for (int nt = 0; nt < 2; ++nt) {
          int p = (wn * 32 + nt * 16 + l16) >> 1;   // N0 multiple of 128 -> head-local
          float val = acc[mt][nt][r];
          float par = __shfl_xor(val, 1);
          float c = cb[p], sn = sb[p];
          float out = (l16 & 1) ? (par * sn + val * c) : (val * c - par * sn);
          Cr[(size_t)(mt * 16 + r) * DIM + nt * 16] = f2bf(out);
        }
      }
  } else {
    // epilogue V: transpose through LDS (staging buffers dead), write vtg[bh][d][s].
    u16 (*T)[256] = reinterpret_cast<u16 (*)[256]>(sm);
    __syncthreads();   // all waves past their last staging-buffer access
#pragma unroll
    for (int mt = 0; mt < 8; ++mt)
#pragma unroll
      for (int nt = 0; nt < 2; ++nt) {
        int col = wn * 32 + nt * 16 + l16;          // d within head: 0..127
        int rowb = (wm * 128 + mt * 16 + quad * 4) ^ ((col & 7) << 3);
        u16x4 p;
        p[0] = f2bf(acc[mt][nt][0]); p[1] = f2bf(acc[mt][nt][1]);
        p[2] = f2bf(acc[mt][nt][2]); p[3] = f2bf(acc[mt][nt][3]);
        *(u16x4*)&T[col][rowb] = p;
      }
    __syncthreads();
    const int b  = M0 >> 11;             // batch
    const int s0 = M0 & (SEQ - 1);
    const int h  = N0 >> 7;              // single head this tile covers
#pragma unroll
    for (int i = 0; i < 8; ++i) {
      int c = i * 512 + tid;             // 4096 16B chunks
      int col = c >> 5;                  // d: 0..127
      int s8 = (c & 31) * 8;             // s offset 0..248
      bf16x8 v8 = *(const bf16x8*)&T[col][s8 ^ ((col & 7) << 3)];
      *(bf16x8*)(vtg + ((size_t)(b * NHEADS + h) * HDIM + col) * SEQ + s0 + s8) = v8;
    }
  }
}

// ---------------------------------------------------------------- output GEMM: same race-fixed
// 2-phase structure (duplicated verbatim). 256 blocks = 1.0 rounds. f32 epilogue.
__global__ __launch_bounds__(512, 2) void gemm_out8(const u16* __restrict__ A,
                                                    const u16* __restrict__ B,
                                                    float* __restrict__ C) {
  __shared__ __align__(16) u16 sm[2 * BUFSZ];   // 96 KiB

  const int tid  = threadIdx.x;
  const int lane = tid & 63, wave = tid >> 6;
  const int l16  = lane & 15, quad = lane >> 4;
  const int wm   = wave >> 2;
  const int wn   = wave & 3;

  // XCD-aware bijective swizzle over 256 blocks (32 per XCD)
  int t = (blockIdx.x & 7) * 32 + (blockIdx.x >> 3);
  const int M0  = (t >> 4) * BM;
  const int N0  = (t & 15) * BN;

  const int u0 = tid, u1 = 512 + tid;
  const int rl0 = u0 >> 3, ch0 = (u0 & 7) ^ (rl0 & 7);
  const int rl1 = u1 >> 3, ch1 = (u1 & 7) ^ (rl1 & 7);

  const int sw  = l16 & 7;
  const int ka0 = (quad ^ sw) * 8;
  const int ka1 = ((4 + quad) ^ sw) * 8;
  const int rowA = (wm * 128 + l16) * BK;
  const int rowB = (wn * 32  + l16) * BK;

#define STGA(h, kt2) do { if ((kt2) < NT) {                                              \
    const u16* _g = A + (size_t)(M0 + (h) * 128) * DIM + (kt2) * BK;                     \
    u16* _l = sm + ((kt2) & 1) * BUFSZ + (h) * 8192 + wave * 512;                        \
    GLL16(_g + (size_t)rl0 * DIM + ch0 * 8, _l);                                         \
    GLL16(_g + (size_t)rl1 * DIM + ch1 * 8, _l + 4096); } } while (0)
#define STGB(kt2) do { if ((kt2) < NT) {                                                 \
    const u16* _g = B + (size_t)N0 * DIM + (kt2) * BK;                                   \
    u16* _l = sm + ((kt2) & 1) * BUFSZ + 16384 + wave * 512;                             \
    GLL16(_g + (size_t)rl0 * DIM + ch0 * 8, _l);                                         \
    GLL16(_g + (size_t)rl1 * DIM + ch1 * 8, _l + 4096); } } while (0)

  STGB(0); STGA(0, 0); STGA(1, 0);
  STGB(1); STGA(0, 1);
  asm volatile("s_waitcnt vmcnt(4)" ::: "memory");
  __builtin_amdgcn_s_barrier();

  fx4 acc[8][2];
#pragma unroll
  for (int m = 0; m < 8; ++m)
#pragma unroll
    for (int n = 0; n < 2; ++n) acc[m][n] = fx4{0.f, 0.f, 0.f, 0.f};

  bf16x8 af[8][2], b0[2], b1[2];

  for (int kt = 0; kt < NT; ++kt) {
    const u16* Ab = sm + (kt & 1) * BUFSZ;
    const u16* Bb = Ab + 16384;

    // ---- ph0
#pragma unroll
    for (int m = 0; m < 8; ++m) {
      af[m][0] = *(const bf16x8*)(Ab + rowA + m * (16 * BK) + ka0);
      af[m][1] = *(const bf16x8*)(Ab + rowA + m * (16 * BK) + ka1);
    }
    b0[0] = *(const bf16x8*)(Bb + rowB + ka0);
    b0[1] = *(const bf16x8*)(Bb + rowB + ka1);
    b1[0] = *(const bf16x8*)(Bb + rowB + 16 * BK + ka0);
    b1[1] = *(const bf16x8*)(Bb + rowB + 16 * BK + ka1);
    STGA(1, kt + 1);
    asm volatile("s_waitcnt lgkmcnt(8)" ::: "memory");
    __builtin_amdgcn_sched_barrier(0);
    __builtin_amdgcn_s_barrier();
    asm volatile("s_waitcnt lgkmcnt(0)" ::: "memory");
    __builtin_amdgcn_sched_barrier(0);
    __builtin_amdgcn_s_setprio(1);
#pragma unroll
    for (int m = 0; m < 4; ++m) {
      acc[m][0] = __builtin_amdgcn_mfma_f32_16x16x32_bf16(af[m][0], b0[0], acc[m][0], 0, 0, 0);
      acc[m][0] = __builtin_amdgcn_mfma_f32_16x16x32_bf16(af[m][1], b0[1], acc[m][0], 0, 0, 0);
      acc[m][1] = __builtin_amdgcn_mfma_f32_16x16x32_bf16(af[m][0], b1[0], acc[m][1], 0, 0, 0);
      acc[m][1] = __builtin_amdgcn_mfma_f32_16x16x32_bf16(af[m][1], b1[1], acc[m][1], 0, 0, 0);
    }
    __builtin_amdgcn_s_setprio(0);
    __builtin_amdgcn_s_barrier();

    // ---- ph1
    STGB(kt + 2);
    STGA(0, kt + 2);
    __builtin_amdgcn_s_setprio(1);
#pragma unroll
    for (int m = 0; m < 4; ++m) {
      acc[m + 4][0] = __builtin_amdgcn_mfma_f32_16x16x32_bf16(af[m + 4][0], b0[0], acc[m + 4][0], 0, 0, 0);
      acc[m + 4][0] = __builtin_amdgcn_mfma_f32_16x16x32_bf16(af[m + 4][1], b0[1], acc[m + 4][0], 0, 0, 0);
      acc[m + 4][1] = __builtin_amdgcn_mfma_f32_16x16x32_bf16(af[m + 4][0], b1[0], acc[m + 4][1], 0, 0, 0);
      acc[m + 4][1] = __builtin_amdgcn_mfma_f32_16x16x32_bf16(af[m + 4][1], b1[1], acc[m + 4][1], 0, 0, 0);
    }
    __builtin_amdgcn_s_setprio(0);
    if (kt < NT - 2) asm volatile("s_waitcnt vmcnt(4)" ::: "memory");
    else             asm volatile("s_waitcnt vmcnt(0)" ::: "memory");
    __builtin_amdgcn_sched_barrier(0);
    __builtin_amdgcn_s_barrier();
  }
#undef STGA
#undef STGB

  // epilogue: f32 C[row=quad*4+r][col=l16] per 16x16 tile
  float* Cr = C + (size_t)(M0 + wm * 128 + quad * 4) * DIM + N0 + wn * 32 + l16;
#pragma unroll
  for (int mt = 0; mt < 8; ++mt)
#pragma unroll
    for (int nt = 0; nt < 2; ++nt)
#pragma unroll
      for (int r = 0; r < 4; ++r)
        Cr[(size_t)(mt * 16 + r) * DIM + nt * 16] = acc[mt][nt][r];
}

// ---------------------------------------------------------------- flash attention, S^T form
// Double-buffered K/V LDS: ONE __syncthreads per K-tile. Defer-max (T13).
struct SMemS { u16 Ks[2][64][136]; u16 Vt[2][128][72]; };
union SMemU { SMemS s; u16 Ot[4][32][136]; };

__global__ __launch_bounds__(256, 2) void attn_kernel(const u16* __restrict__ qm,
                                                      const u16* __restrict__ km,
                                                      const u16* __restrict__ vtg,
                                                      u16* __restrict__ ao) {
  __shared__ __align__(16) SMemU sm;
  const int tid = threadIdx.x;
  const int lane = tid & 63, wave = tid >> 6;
  const int l16 = lane & 15, quad = lane >> 4;
  const int idx = blockIdx.x;
  const int bh = idx & 31;
  const int j = idx >> 5;
  const int qt = (j < 8) ? (15 - j) : (j - 8);   // complementary pairing
  const int b = bh >> 4, h = bh & 15;
  const int q0 = qt * 128;
  const size_t brow = (size_t)b * SEQ;
  const int hc = h * HDIM;
  const size_t vbase = (size_t)bh * HDIM * SEQ;
  const int nkt = 2 * qt + 2;

  // Q as B-operand frags: B[n=q=l16][k=d=quad*8+j]
  bf16x8 aq[2][4];
#pragma unroll
  for (int nt = 0; nt < 2; ++nt) {
    size_t qbase = (brow + q0 + wave * 32 + nt * 16 + l16) * DIM + hc;
#pragma unroll
    for (int dc = 0; dc < 4; ++dc)
      aq[nt][dc] = *(const bf16x8*)(qm + qbase + dc * 32 + quad * 8);
  }
  fx4 o[2][8];   // O^T tiles: [q-tile][d-tile], C-layout col=q=l16, row=d=quad*4+r
#pragma unroll
  for (int nt = 0; nt < 2; ++nt)
#pragma unroll
    for (int dt = 0; dt < 8; ++dt) o[nt][dt] = fx4{0.f, 0.f, 0.f, 0.f};
  float mr[2] = {-3e38f, -3e38f}, lr[2] = {0.f, 0.f};   // per-lane: q = l16 of each tile

  bf16x8 kreg[4], vreg[4];
  // tile 0 -> regs -> buf0
#pragma unroll
  for (int i = 0; i < 4; ++i) {
    int c = i * 256 + tid;
    kreg[i] = *(const bf16x8*)(km + (brow + (c >> 4)) * DIM + hc + (c & 15) * 8);
    vreg[i] = *(const bf16x8*)(vtg + vbase + (size_t)(c >> 3) * SEQ + (c & 7) * 8);
  }
#pragma unroll
  for (int i = 0; i < 4; ++i) {
    int c = i * 256 + tid;
    *(bf16x8*)&sm.s.Ks[0][c >> 4][(c & 15) * 8] = kreg[i];
    *(bf16x8*)&sm.s.Vt[0][c >> 3][(c & 7) * 8] = vreg[i];
  }
  // tile 1 -> regs (issue early)
  if (1 < nkt) {
#pragma unroll
    for (int i = 0; i < 4; ++i) {
      int c = i * 256 + tid;
      kreg[i] = *(const bf16x8*)(km + (brow + 64 + (c >> 4)) * DIM + hc + (c & 15) * 8);
      vreg[i] = *(const bf16x8*)(vtg + vbase + (size_t)(c >> 3) * SEQ + 64 + (c & 7) * 8);
    }
  }
  __syncthreads();

  for (int kt = 0; kt < nkt; ++kt) {
    const int cur = kt & 1;
    // store tile kt+1 into the other buffer (its last readers finished at prev barrier)
    if (kt + 1 < nkt) {
#pragma unroll
      for (int i = 0; i < 4; ++i) {
        int c = i * 256 + tid;
        *(bf16x8*)&sm.s.Ks[cur ^ 1][c >> 4][(c & 15) * 8] = kreg[i];
        *(bf16x8*)&sm.s.Vt[cur ^ 1][c >> 3][(c & 7) * 8] = vreg[i];
      }
    }
    // issue tile kt+2 global loads (HBM latency hides under compute below)
    if (kt + 2 < nkt) {
      const int kv2 = (kt + 2) * 64;
#pragma unroll
      for (int i = 0; i < 4; ++i) {
        int c = i * 256 + tid;
        kreg[i] = *(const bf16x8*)(km + (brow + kv2 + (c >> 4)) * DIM + hc + (c & 15) * 8);
        vreg[i] = *(const bf16x8*)(vtg + vbase + (size_t)(c >> 3) * SEQ + kv2 + (c & 7) * 8);
      }
    }
    // S^T = K Q^T : A = K frag (m=kv), B = Q frag (n=q). s[nt][tm]: kv=tm*16+quad*4+r, q=l16
    fx4 s[2][4];
#pragma unroll
    for (int tm = 0; tm < 4; ++tm) {
      fx4 a0 = fx4{0.f, 0.f, 0.f, 0.f}, a1 = fx4{0.f, 0.f, 0.f, 0.f};
#pragma unroll
      for (int dc = 0; dc < 4; ++dc) {
        bf16x8 kf = *(const bf16x8*)&sm.s.Ks[cur][tm * 16 + l16][dc * 32 + quad * 8];
        a0 = __builtin_amdgcn_mfma_f32_16x16x32_bf16(kf, aq[0][dc], a0, 0, 0, 0);
        a1 = __builtin_amdgcn_mfma_f32_16x16x32_bf16(kf, aq[1][dc], a1, 0, 0, 0);
      }
      s[0][tm] = a0 * 0.08838834764831845f;
      s[1][tm] = a1 * 0.08838834764831845f;
    }
    // causal mask (only tiles touching the diagonal)
    if (kt >= nkt - 2) {
      const int kv0 = kt * 64;
#pragma unroll
      for (int nt = 0; nt < 2; ++nt) {
        int qpos = q0 + wave * 32 + nt * 16 + l16;
#pragma unroll
        for (int tm = 0; tm < 4; ++tm)
#pragma unroll
          for (int r = 0; r < 4; ++r)
            if (kv0 + tm * 16 + quad * 4 + r > qpos) s[nt][tm][r] = -1e30f;
      }
    }
    // online softmax over kv (regs + quads); q = l16 per tile; defer-max (T13)
    bf16x4 pf[2][4];
#pragma unroll
    for (int nt = 0; nt < 2; ++nt) {
      float t = -3e38f;
#pragma unroll
      for (int tm = 0; tm < 4; ++tm)
        t = fmaxf(t, fmaxf(fmaxf(s[nt][tm][0], s[nt][tm][1]),
                           fmaxf(s[nt][tm][2], s[nt][tm][3])));
      t = fmaxf(t, __shfl_xor(t, 16));
      t = fmaxf(t, __shfl_xor(t, 32));
      if (!__all(t - mr[nt] <= 8.f)) {
        float mnew = fmaxf(mr[nt], t);
        float alpha = __expf(mr[nt] - mnew);
        lr[nt] *= alpha;
        mr[nt] = mnew;
#pragma unroll
        for (int dt = 0; dt < 8; ++dt) o[nt][dt] *= alpha;
      }
      float sum = 0.f;
#pragma unroll
      for (int tm = 0; tm < 4; ++tm) {
        fx4 p;
#pragma unroll
        for (int r = 0; r < 4; ++r) {
          p[r] = __expf(s[nt][tm][r] - mr[nt]);
          sum += p[r];
        }
        bf16x4 pb;
        pb[0] = (short)f2bf(p[0]); pb[1] = (short)f2bf(p[1]);
        pb[2] = (short)f2bf(p[2]); pb[3] = (short)f2bf(p[3]);
        pf[nt][tm] = pb;
      }
      sum += __shfl_xor(sum, 16);
      sum += __shfl_xor(sum, 32);
      lr[nt] += sum;
    }
    // O^T += V^T P^T : A = V^T frag (m=d, k=kv=quad*4+j, b64), B = pf (registers!)
#pragma unroll
    for (int tm = 0; tm < 4; ++tm) {
#pragma unroll
      for (int dt = 0; dt < 8; ++dt) {
        bf16x4 vf = *(const bf16x4*)&sm.s.Vt[cur][dt * 16 + l16][tm * 16 + quad * 4];
        o[0][dt] = __builtin_amdgcn_mfma_f32_16x16x16bf16_1k(vf, pf[0][tm], o[0][dt], 0, 0, 0);
        o[1][dt] = __builtin_amdgcn_mfma_f32_16x16x16bf16_1k(vf, pf[1][tm], o[1][dt], 0, 0, 0);
      }
    }
    __syncthreads();   // seal this step's reads and tile-(kt+1) writes
  }
  // epilogue: O^T -> LDS transpose (reuse tile memory) -> coalesced global
#pragma unroll
  for (int nt = 0; nt < 2; ++nt) {
    float inv = 1.f / lr[nt];
#pragma unroll
    for (int dt = 0; dt < 8; ++dt) {
      fx4 v = o[nt][dt];
      u16x4 p;
      p[0] = f2bf(v[0] * inv); p[1] = f2bf(v[1] * inv);
      p[2] = f2bf(v[2] * inv); p[3] = f2bf(v[3] * inv);
      *(u16x4*)&sm.Ot[wave][nt * 16 + l16][dt * 16 + quad * 4] = p;
    }
  }
  // wave-private region: compiler's lgkmcnt ordering suffices (no barrier)
#pragma unroll
  for (int i = 0; i < 8; ++i) {
    int c = i * 64 + lane;
    int row = c >> 4;          // 0..31
    int ch = c & 15;           // 16B chunks across 128 d
    bf16x8 t = *(const bf16x8*)&sm.Ot[wave][row][ch * 8];
    *(bf16x8*)(ao + (brow + q0 + wave * 32 + row) * DIM + hc + ch * 8) = t;
  }
}

// ---------------------------------------------------------------- launch
extern "C" void kernel_launch(void* const* d_in, const int* in_sizes, int n_in,
                              void* d_out, int out_size, void* d_ws, size_t ws_size,
                              hipStream_t stream) {
  const float* x    = (const float*)d_in[0];
  const float* fcos = (const float*)d_in[2];
  const float* fsin = (const float*)d_in[3];
  const float* wq   = (const float*)d_in[5];
  const float* wk   = (const float*)d_in[6];
  const float* wv   = (const float*)d_in[7];
  const float* wo   = (const float*)d_in[8];
  float* out = (float*)d_out;

  const size_t XN = (size_t)ROWS * DIM;
  const size_t WN = (size_t)DIM * DIM;
  u16* ws  = (u16*)d_ws;
  u16* xb  = ws;
  u16* wqb = xb + XN;
  u16* wkb = wqb + WN;
  u16* wvb = wkb + WN;
  u16* wob = wvb + WN;
  u16* q   = wob + WN;
  u16* k   = q + XN;
  u16* vtg = k + XN;   // V written pre-transposed by gemm_qkv8 (old v slot)
  u16* ao  = vtg + XN;

  const int total_chunks = (int)((XN + 4 * WN) / 4);
  cvt5_kernel<<<total_chunks / 256, 256, 0, stream>>>(x, wq, wk, wv, wo, ws);

  gemm_qkv8<<<dim3(768), 512, 0, stream>>>(xb, wqb, wkb, wvb, q, k, vtg, fcos, fsin);

  attn_kernel<<<dim3(512), 256, 0, stream>>>(q, k, vtg, ao);

  gemm_out8<<<dim3(256), 512, 0, stream>>>(ao, wob, out);
}